// Round 6
// baseline (164.111 us; speedup 1.0000x reference)
//
#include <hip/hip_runtime.h>
#include <hip/hip_bf16.h>
#include <math.h>

typedef unsigned short u16;
typedef __bf16 bf16x8 __attribute__((ext_vector_type(8)));
typedef float f32x4 __attribute__((ext_vector_type(4)));
typedef unsigned short u16x4 __attribute__((ext_vector_type(4)));

#define NROW 4096
#define KDIM 1024
#define MDIM 8192
#define TILE 128
#define BK 64
#define NT   (NROW / TILE)            // 32 tiles per dim
#define NSEG (NT * 2)                 // 64 col-segments of 64 cols
#define NTRI (NT * (NT + 1) / 2)      // 528 upper-triangle tiles = 8 * 66
#define NBLK (NROW + NTRI)            // 4624 fused blocks

__device__ __forceinline__ u16 f2bf(float x) {
    unsigned int u = __float_as_uint(x);
    unsigned int r = (u + 0x7fffu + ((u >> 16) & 1u)) >> 16;
    return (u16)r;
}

__device__ __forceinline__ void gload16(const u16* g, u16* l) {
    __builtin_amdgcn_global_load_lds(
        (const __attribute__((address_space(1))) void*)g,
        (__attribute__((address_space(3))) void*)l,
        16, 0, 0);
}

// ---------------- Kernel A: row-normalize q -> bf16 (must precede gemm: kernel
// boundary is the only safe cross-XCD visibility for qn) ----------------
__global__ void k_normalize(const float* __restrict__ q, u16* __restrict__ qn) {
    const int r = blockIdx.x;
    const int t = threadIdx.x;          // 256 threads
    const int lane = t & 63, wid = t >> 6;
    const float4* qr = (const float4*)(q + (size_t)r * KDIM);
    float4 v = qr[t];
    float ss = v.x * v.x + v.y * v.y + v.z * v.z + v.w * v.w;
    #pragma unroll
    for (int d = 1; d < 64; d <<= 1) ss += __shfl_xor(ss, d);
    __shared__ float red[4];
    if (lane == 0) red[wid] = ss;
    __syncthreads();
    float tot = red[0] + red[1] + red[2] + red[3];
    float inv = 1.0f / fmaxf(sqrtf(tot), 1e-8f);
    u16x4 o;
    o[0] = f2bf(v.x * inv); o[1] = f2bf(v.y * inv);
    o[2] = f2bf(v.z * inv); o[3] = f2bf(v.w * inv);
    *(u16x4*)(qn + (size_t)r * KDIM + t * 4) = o;
}

// ---------------- Fused kernel: memstats stream + symmetric GEMM ----------------
// bid decode: g=bid>>3, r=bid&7.
//   gemm iff g<528 && r==(g&7)  -> gemm index g (round-robins XCDs; XCD x gets
//                                  enumeration slice e = x*66 + (g>>3), L2-coherent)
//   else stream row = bid - [min(g,528) + (g<528 && r>(g&7) ? 1 : 0)]
__global__ void k_fused(const u16* __restrict__ qn, const int* __restrict__ labels,
                        const float* __restrict__ ml, const float* __restrict__ mt,
                        float4* __restrict__ partials, float4* __restrict__ memq) {
    __shared__ u16 ldsA[TILE * BK];
    __shared__ u16 ldsB[TILE * BK];
    __shared__ int labR[TILE], labC[TILE];

    const int bid = blockIdx.x;
    const int t = threadIdx.x;
    const int w = t >> 6, lane = t & 63;
    const int g = bid >> 3, rr8 = bid & 7;
    const bool is_gemm = (g < NTRI) && (rr8 == (g & 7));

    if (!is_gemm) {
        // ---------------- stream path: one ml/mt row, proven 8-deep pattern ----------------
        const int r = bid - (min(g, NTRI) + ((g < NTRI && rr8 > (g & 7)) ? 1 : 0));
        const float4* pl = (const float4*)(ml + (size_t)r * MDIM);
        const float4* pt = (const float4*)(mt + (size_t)r * MDIM);
        float S2 = 0.f, dot = 0.f, smt = 0.f;
        #pragma unroll
        for (int it = 0; it < 2; ++it) {
            const int i0 = it * 1024 + t;
            float4 l0 = pl[i0], l1 = pl[i0 + 256], l2 = pl[i0 + 512], l3 = pl[i0 + 768];
            float4 t0 = pt[i0], t1 = pt[i0 + 256], t2 = pt[i0 + 512], t3 = pt[i0 + 768];
            S2 += __expf(l0.x) + __expf(l0.y) + __expf(l0.z) + __expf(l0.w);
            S2 += __expf(l1.x) + __expf(l1.y) + __expf(l1.z) + __expf(l1.w);
            S2 += __expf(l2.x) + __expf(l2.y) + __expf(l2.z) + __expf(l2.w);
            S2 += __expf(l3.x) + __expf(l3.y) + __expf(l3.z) + __expf(l3.w);
            dot += t0.x * l0.x + t0.y * l0.y + t0.z * l0.z + t0.w * l0.w;
            dot += t1.x * l1.x + t1.y * l1.y + t1.z * l1.z + t1.w * l1.w;
            dot += t2.x * l2.x + t2.y * l2.y + t2.z * l2.z + t2.w * l2.w;
            dot += t3.x * l3.x + t3.y * l3.y + t3.z * l3.z + t3.w * l3.w;
            smt += t0.x + t0.y + t0.z + t0.w + t1.x + t1.y + t1.z + t1.w;
            smt += t2.x + t2.y + t2.z + t2.w + t3.x + t3.y + t3.z + t3.w;
        }
        #pragma unroll
        for (int d = 1; d < 64; d <<= 1) {
            S2  += __shfl_xor(S2, d);
            dot += __shfl_xor(dot, d);
            smt += __shfl_xor(smt, d);
        }
        __shared__ float red[4][3];
        const int wid = t >> 6;
        if (lane == 0) { red[wid][0] = S2; red[wid][1] = dot; red[wid][2] = smt; }
        __syncthreads();
        if (t == 0)
            memq[r] = make_float4(red[0][0] + red[1][0] + red[2][0] + red[3][0],
                                  red[0][1] + red[1][1] + red[2][1] + red[3][1],
                                  red[0][2] + red[1][2] + red[2][2] + red[3][2], 0.f);
        return;
    }

    // ---------------- GEMM path ----------------
    // XCD-banded enumeration: e in [0,528), XCD (g&7) owns a contiguous 66-slot slice.
    int e = (g & 7) * 66 + (g >> 3);
    // chunk order (rb,cb): (0,0)(0,1)(1,1)(0,2)(1,2)(2,2)(0,3)(1,3)(2,3)(3,3)
    int rb, cb, base;
    if      (e < 36)  { rb = 0; cb = 0; base = 0;   }
    else if (e < 100) { rb = 0; cb = 1; base = 36;  }
    else if (e < 136) { rb = 1; cb = 1; base = 100; }
    else if (e < 200) { rb = 0; cb = 2; base = 136; }
    else if (e < 264) { rb = 1; cb = 2; base = 200; }
    else if (e < 300) { rb = 2; cb = 2; base = 264; }
    else if (e < 364) { rb = 0; cb = 3; base = 300; }
    else if (e < 428) { rb = 1; cb = 3; base = 364; }
    else if (e < 492) { rb = 2; cb = 3; base = 428; }
    else              { rb = 3; cb = 3; base = 492; }
    int k = e - base;
    int bi, ct;
    if (rb == cb) {                       // triangular 8x8 chunk, k in [0,36)
        int b2 = 0, kk = k;
        while (kk >= 8 - b2) { kk -= 8 - b2; ++b2; }
        bi = rb * 8 + b2; ct = cb * 8 + b2 + kk;
    } else {                              // full 8x8 chunk
        bi = rb * 8 + (k >> 3); ct = cb * 8 + (k & 7);
    }

    const int rowbase = bi * TILE, colbase = ct * TILE;

    if (t < 128) labR[t] = labels[rowbase + t];
    else labC[t - 128] = labels[colbase + (t - 128)];

    const int wr = (w >> 1) * 64, wc = (w & 1) * 64;
    const int cl = lane & 15, cg = lane >> 4;
    const int sr = lane >> 3, skb = lane & 7;

    f32x4 acc[4][4];
    #pragma unroll
    for (int i = 0; i < 4; ++i)
        #pragma unroll
        for (int j = 0; j < 4; ++j)
            acc[i][j] = {0.f, 0.f, 0.f, 0.f};

    for (int ks = 0; ks < KDIM / BK; ++ks) {
        const int k0 = ks * BK;
        #pragma unroll
        for (int it = 0; it < 4; ++it) {
            int c = w * 4 + it;
            int rw = c * 8 + sr;
            gload16(qn + (size_t)(rowbase + rw) * KDIM + k0 + skb * 8, ldsA + c * 512);
            gload16(qn + (size_t)(colbase + rw) * KDIM + k0 + skb * 8, ldsB + c * 512);
        }
        asm volatile("s_waitcnt vmcnt(0)" ::: "memory");
        __syncthreads();
        #pragma unroll
        for (int k2 = 0; k2 < 2; ++k2) {
            bf16x8 a[4], b[4];
            #pragma unroll
            for (int f = 0; f < 4; ++f) {
                a[f] = *(const bf16x8*)&ldsA[(wr + f * 16 + cl) * BK + k2 * 32 + cg * 8];
                b[f] = *(const bf16x8*)&ldsB[(wc + f * 16 + cl) * BK + k2 * 32 + cg * 8];
            }
            #pragma unroll
            for (int fm = 0; fm < 4; ++fm)
                #pragma unroll
                for (int fn = 0; fn < 4; ++fn)
                    acc[fm][fn] = __builtin_amdgcn_mfma_f32_16x16x32_bf16(
                        a[fm], b[fn], acc[fm][fn], 0, 0, 0);
        }
        __syncthreads();
    }

    const float invT = (float)(1.0 / 0.07);

    // ---- direct: row stats over this wave's 64 cols -> segment ct*2 + (w&1) ----
    // C-layout (m89): col = lane&15, row = (lane>>4)*4 + reg.
    #pragma unroll
    for (int fm = 0; fm < 4; ++fm) {
        #pragma unroll
        for (int reg = 0; reg < 4; ++reg) {
            const int lr = wr + fm * 16 + cg * 4 + reg;
            const int gi = rowbase + lr;
            const int li = labR[lr];
            float c0 = acc[fm][0][reg] * invT;
            float c1 = acc[fm][1][reg] * invT;
            float c2 = acc[fm][2][reg] * invT;
            float c3 = acc[fm][3][reg] * invT;
            float m = fmaxf(fmaxf(c0, c1), fmaxf(c2, c3));
            #pragma unroll
            for (int d = 1; d < 16; d <<= 1) m = fmaxf(m, __shfl_xor(m, d));
            float se = 0.f, ps = 0.f, cnt = 0.f;
            #pragma unroll
            for (int fn = 0; fn < 4; ++fn) {
                float c = (fn == 0) ? c0 : (fn == 1) ? c1 : (fn == 2) ? c2 : c3;
                const int lc = wc + fn * 16 + cl;
                const bool self = (colbase + lc == gi);
                se += self ? 0.f : __expf(c - m);
                const bool pos = (!self) && (labC[lc] == li);
                ps += pos ? c : 0.f;
                cnt += pos ? 1.f : 0.f;
            }
            #pragma unroll
            for (int d = 1; d < 16; d <<= 1) {
                se  += __shfl_xor(se, d);
                ps  += __shfl_xor(ps, d);
                cnt += __shfl_xor(cnt, d);
            }
            if (cl == 0)
                partials[(size_t)(ct * 2 + (w & 1)) * NROW + gi] =
                    make_float4(m, se, ps, cnt);
        }
    }

    // ---- transposed (bi < ct): col stats over this wave's 64 rows -> segment bi*2 + (w>>1) ----
    if (bi != ct) {
        #pragma unroll
        for (int fn = 0; fn < 4; ++fn) {
            const int lc = wc + fn * 16 + cl;
            const int gj = colbase + lc;
            const int lj = labC[lc];
            float m = -3.4e38f;
            #pragma unroll
            for (int fm = 0; fm < 4; ++fm)
                #pragma unroll
                for (int reg = 0; reg < 4; ++reg)
                    m = fmaxf(m, acc[fm][fn][reg] * invT);
            m = fmaxf(m, __shfl_xor(m, 16));
            m = fmaxf(m, __shfl_xor(m, 32));
            float se = 0.f, ps = 0.f, cnt = 0.f;
            #pragma unroll
            for (int fm = 0; fm < 4; ++fm) {
                #pragma unroll
                for (int reg = 0; reg < 4; ++reg) {
                    float c = acc[fm][fn][reg] * invT;
                    const int lr = wr + fm * 16 + cg * 4 + reg;
                    se += __expf(c - m);            // bi<ct: never self
                    const bool pos = (labR[lr] == lj);
                    ps += pos ? c : 0.f;
                    cnt += pos ? 1.f : 0.f;
                }
            }
            se += __shfl_xor(se, 16); ps += __shfl_xor(ps, 16); cnt += __shfl_xor(cnt, 16);
            se += __shfl_xor(se, 32); ps += __shfl_xor(ps, 32); cnt += __shfl_xor(cnt, 32);
            if (cg == 0)
                partials[(size_t)(bi * 2 + (w >> 1)) * NROW + gj] =
                    make_float4(m, se, ps, cnt);
        }
    }
}

// ---------------- Kernel D: per-row combine ----------------
__global__ void k_combine(const float4* __restrict__ partials, const float4* __restrict__ memq,
                          float* __restrict__ vals) {
    const int r = blockIdx.x * blockDim.x + threadIdx.x;
    if (r >= NROW) return;
    float M = -3.4e38f;
    #pragma unroll 8
    for (int s = 0; s < NSEG; ++s) M = fmaxf(M, partials[(size_t)s * NROW + r].x);
    float S1 = 0.f, ps = 0.f, cnt = 0.f;
    #pragma unroll 8
    for (int s = 0; s < NSEG; ++s) {
        float4 p = partials[(size_t)s * NROW + r];
        S1 += p.y * __expf(p.x - M);
        ps += p.z;
        cnt += p.w;
    }
    float4 mq = memq[r];
    float L = logf(S1 + mq.x);
    vals[r] = (ps - cnt * (M + L) + mq.y - mq.z * L) / (cnt + mq.z);
}

// ---------------- Kernel E: final scalar ----------------
__global__ void k_finalize(const float* __restrict__ vals, float* __restrict__ out) {
    const int t = threadIdx.x;          // 256
    const int lane = t & 63, wid = t >> 6;
    float s = 0.f;
    for (int i = t; i < NROW; i += 256) s += vals[i];
    #pragma unroll
    for (int d = 1; d < 64; d <<= 1) s += __shfl_xor(s, d);
    __shared__ float red[4];
    if (lane == 0) red[wid] = s;
    __syncthreads();
    if (t == 0) out[0] = -(red[0] + red[1] + red[2] + red[3]) * (1.0f / (float)NROW);
}

extern "C" void kernel_launch(void* const* d_in, const int* in_sizes, int n_in,
                              void* d_out, int out_size, void* d_ws, size_t ws_size,
                              hipStream_t stream) {
    const float* q  = (const float*)d_in[0];
    const int* labels = (const int*)d_in[1];
    const float* ml = (const float*)d_in[2];
    const float* mt = (const float*)d_in[3];
    float* out = (float*)d_out;

    char* w = (char*)d_ws;
    u16* qn          = (u16*)w;                      //  8,388,608 B
    float4* partials = (float4*)(w + 8388608);       //  4,194,304 B (64 segs)
    float4* memq     = (float4*)(w + 12582912);      //     65,536 B
    float* vals      = (float*)(w + 12648448);       //     16,384 B

    k_normalize<<<NROW, 256, 0, stream>>>(q, qn);
    k_fused<<<NBLK, 256, 0, stream>>>(qn, labels, ml, mt, partials, memq);
    k_combine<<<NROW / 256, 256, 0, stream>>>(partials, memq, vals);
    k_finalize<<<1, 256, 0, stream>>>(vals, out);
}

// Round 7
// 112.408 us; speedup vs baseline: 1.4600x; 1.4600x over previous
//
#include <hip/hip_runtime.h>
#include <hip/hip_bf16.h>
#include <math.h>

typedef unsigned short u16;
typedef __bf16 bf16x8 __attribute__((ext_vector_type(8)));
typedef float f32x4 __attribute__((ext_vector_type(4)));
typedef unsigned short u16x4 __attribute__((ext_vector_type(4)));

#define NROW 4096
#define KDIM 1024
#define MDIM 8192
#define TILE 128
#define BK 64
#define NT   (NROW / TILE)            // 32 tiles per dim
#define NSEG (NT * 2)                 // 64 col-segments of 64 cols
#define NTRI (NT * (NT + 1) / 2)      // 528 upper-triangle tiles = 8 * 66

__device__ __forceinline__ u16 f2bf(float x) {
    unsigned int u = __float_as_uint(x);
    unsigned int r = (u + 0x7fffu + ((u >> 16) & 1u)) >> 16;
    return (u16)r;
}

__device__ __forceinline__ void gload16(const u16* g, u16* l) {
    __builtin_amdgcn_global_load_lds(
        (const __attribute__((address_space(1))) void*)g,
        (__attribute__((address_space(3))) void*)l,
        16, 0, 0);
}

// ---------------- Kernel A+B fused: normalize row r AND memstats row r ----------------
// Stream loads are NON-TEMPORAL (nt): single-use 268 MB stream should not
// allocate into L3 — tests the L3-fill-contention hypothesis for the ~3.3 TB/s cap.
__global__ void k_norm_mem(const float* __restrict__ q,
                           const float* __restrict__ ml, const float* __restrict__ mt,
                           u16* __restrict__ qn, float4* __restrict__ memq) {
    const int r = blockIdx.x;
    const int t = threadIdx.x;          // 256
    const int lane = t & 63, wid = t >> 6;

    // --- issue q load + square-sum ---
    const float4* qr = (const float4*)(q + (size_t)r * KDIM);
    float4 v = qr[t];
    float ss = v.x * v.x + v.y * v.y + v.z * v.z + v.w * v.w;

    // --- memstats streaming (the big read), nt loads ---
    const f32x4* pl = (const f32x4*)(ml + (size_t)r * MDIM);
    const f32x4* pt = (const f32x4*)(mt + (size_t)r * MDIM);
    float S2 = 0.f, dot = 0.f, smt = 0.f;
    #pragma unroll
    for (int it = 0; it < 2; ++it) {
        const int i0 = it * 1024 + t;
        f32x4 l0 = __builtin_nontemporal_load(pl + i0);
        f32x4 l1 = __builtin_nontemporal_load(pl + i0 + 256);
        f32x4 l2 = __builtin_nontemporal_load(pl + i0 + 512);
        f32x4 l3 = __builtin_nontemporal_load(pl + i0 + 768);
        f32x4 t0 = __builtin_nontemporal_load(pt + i0);
        f32x4 t1 = __builtin_nontemporal_load(pt + i0 + 256);
        f32x4 t2 = __builtin_nontemporal_load(pt + i0 + 512);
        f32x4 t3 = __builtin_nontemporal_load(pt + i0 + 768);
        S2 += __expf(l0.x) + __expf(l0.y) + __expf(l0.z) + __expf(l0.w);
        S2 += __expf(l1.x) + __expf(l1.y) + __expf(l1.z) + __expf(l1.w);
        S2 += __expf(l2.x) + __expf(l2.y) + __expf(l2.z) + __expf(l2.w);
        S2 += __expf(l3.x) + __expf(l3.y) + __expf(l3.z) + __expf(l3.w);
        dot += t0.x * l0.x + t0.y * l0.y + t0.z * l0.z + t0.w * l0.w;
        dot += t1.x * l1.x + t1.y * l1.y + t1.z * l1.z + t1.w * l1.w;
        dot += t2.x * l2.x + t2.y * l2.y + t2.z * l2.z + t2.w * l2.w;
        dot += t3.x * l3.x + t3.y * l3.y + t3.z * l3.z + t3.w * l3.w;
        smt += t0.x + t0.y + t0.z + t0.w + t1.x + t1.y + t1.z + t1.w;
        smt += t2.x + t2.y + t2.z + t2.w + t3.x + t3.y + t3.z + t3.w;
    }

    // --- finish normalize ---
    #pragma unroll
    for (int d = 1; d < 64; d <<= 1) ss += __shfl_xor(ss, d);
    __shared__ float redn[4];
    if (lane == 0) redn[wid] = ss;
    __syncthreads();
    float tot = redn[0] + redn[1] + redn[2] + redn[3];
    float inv = 1.0f / fmaxf(sqrtf(tot), 1e-8f);
    u16x4 o;
    o[0] = f2bf(v.x * inv); o[1] = f2bf(v.y * inv);
    o[2] = f2bf(v.z * inv); o[3] = f2bf(v.w * inv);
    *(u16x4*)(qn + (size_t)r * KDIM + t * 4) = o;

    // --- finish memstats ---
    #pragma unroll
    for (int d = 1; d < 64; d <<= 1) {
        S2  += __shfl_xor(S2, d);
        dot += __shfl_xor(dot, d);
        smt += __shfl_xor(smt, d);
    }
    __shared__ float red[4][3];
    if (lane == 0) { red[wid][0] = S2; red[wid][1] = dot; red[wid][2] = smt; }
    __syncthreads();
    if (t == 0)
        memq[r] = make_float4(red[0][0] + red[1][0] + red[2][0] + red[3][0],
                              red[0][1] + red[1][1] + red[2][1] + red[3][1],
                              red[0][2] + red[1][2] + red[2][2] + red[3][2], 0.f);
}

// ---------------- Kernel C: symmetric sims GEMM + fused segment stats ----------------
// XCD-banded enumeration (unchanged from R5).
__global__ void k_gemm_sym(const u16* __restrict__ qn, const int* __restrict__ labels,
                           float4* __restrict__ partials) {
    __shared__ u16 ldsA[TILE * BK];
    __shared__ u16 ldsB[TILE * BK];
    __shared__ int labR[TILE], labC[TILE];

    const int bid = blockIdx.x;
    int e = (bid & 7) * 66 + (bid >> 3);   // enumeration index in [0,528)
    int rb, cb, base;
    if      (e < 36)  { rb = 0; cb = 0; base = 0;   }
    else if (e < 100) { rb = 0; cb = 1; base = 36;  }
    else if (e < 136) { rb = 1; cb = 1; base = 100; }
    else if (e < 200) { rb = 0; cb = 2; base = 136; }
    else if (e < 264) { rb = 1; cb = 2; base = 200; }
    else if (e < 300) { rb = 2; cb = 2; base = 264; }
    else if (e < 364) { rb = 0; cb = 3; base = 300; }
    else if (e < 428) { rb = 1; cb = 3; base = 364; }
    else if (e < 492) { rb = 2; cb = 3; base = 428; }
    else              { rb = 3; cb = 3; base = 492; }
    int k = e - base;
    int bi, ct;
    if (rb == cb) {
        int b2 = 0, kk = k;
        while (kk >= 8 - b2) { kk -= 8 - b2; ++b2; }
        bi = rb * 8 + b2; ct = cb * 8 + b2 + kk;
    } else {
        bi = rb * 8 + (k >> 3); ct = cb * 8 + (k & 7);
    }

    const int t = threadIdx.x;
    const int w = t >> 6, lane = t & 63;
    const int rowbase = bi * TILE, colbase = ct * TILE;

    if (t < 128) labR[t] = labels[rowbase + t];
    else labC[t - 128] = labels[colbase + (t - 128)];

    const int wr = (w >> 1) * 64, wc = (w & 1) * 64;
    const int cl = lane & 15, cg = lane >> 4;
    const int sr = lane >> 3, skb = lane & 7;

    f32x4 acc[4][4];
    #pragma unroll
    for (int i = 0; i < 4; ++i)
        #pragma unroll
        for (int j = 0; j < 4; ++j)
            acc[i][j] = {0.f, 0.f, 0.f, 0.f};

    for (int ks = 0; ks < KDIM / BK; ++ks) {
        const int k0 = ks * BK;
        #pragma unroll
        for (int it = 0; it < 4; ++it) {
            int c = w * 4 + it;
            int rw = c * 8 + sr;
            gload16(qn + (size_t)(rowbase + rw) * KDIM + k0 + skb * 8, ldsA + c * 512);
            gload16(qn + (size_t)(colbase + rw) * KDIM + k0 + skb * 8, ldsB + c * 512);
        }
        asm volatile("s_waitcnt vmcnt(0)" ::: "memory");
        __syncthreads();
        #pragma unroll
        for (int k2 = 0; k2 < 2; ++k2) {
            bf16x8 a[4], b[4];
            #pragma unroll
            for (int f = 0; f < 4; ++f) {
                a[f] = *(const bf16x8*)&ldsA[(wr + f * 16 + cl) * BK + k2 * 32 + cg * 8];
                b[f] = *(const bf16x8*)&ldsB[(wc + f * 16 + cl) * BK + k2 * 32 + cg * 8];
            }
            #pragma unroll
            for (int fm = 0; fm < 4; ++fm)
                #pragma unroll
                for (int fn = 0; fn < 4; ++fn)
                    acc[fm][fn] = __builtin_amdgcn_mfma_f32_16x16x32_bf16(
                        a[fm], b[fn], acc[fm][fn], 0, 0, 0);
        }
        __syncthreads();
    }

    const float invT = (float)(1.0 / 0.07);

    // ---- direct: row stats over this wave's 64 cols -> segment ct*2 + (w&1) ----
    #pragma unroll
    for (int fm = 0; fm < 4; ++fm) {
        #pragma unroll
        for (int reg = 0; reg < 4; ++reg) {
            const int lr = wr + fm * 16 + cg * 4 + reg;
            const int gi = rowbase + lr;
            const int li = labR[lr];
            float c0 = acc[fm][0][reg] * invT;
            float c1 = acc[fm][1][reg] * invT;
            float c2 = acc[fm][2][reg] * invT;
            float c3 = acc[fm][3][reg] * invT;
            float m = fmaxf(fmaxf(c0, c1), fmaxf(c2, c3));
            #pragma unroll
            for (int d = 1; d < 16; d <<= 1) m = fmaxf(m, __shfl_xor(m, d));
            float se = 0.f, ps = 0.f, cnt = 0.f;
            #pragma unroll
            for (int fn = 0; fn < 4; ++fn) {
                float c = (fn == 0) ? c0 : (fn == 1) ? c1 : (fn == 2) ? c2 : c3;
                const int lc = wc + fn * 16 + cl;
                const bool self = (colbase + lc == gi);
                se += self ? 0.f : __expf(c - m);
                const bool pos = (!self) && (labC[lc] == li);
                ps += pos ? c : 0.f;
                cnt += pos ? 1.f : 0.f;
            }
            #pragma unroll
            for (int d = 1; d < 16; d <<= 1) {
                se  += __shfl_xor(se, d);
                ps  += __shfl_xor(ps, d);
                cnt += __shfl_xor(cnt, d);
            }
            if (cl == 0)
                partials[(size_t)(ct * 2 + (w & 1)) * NROW + gi] =
                    make_float4(m, se, ps, cnt);
        }
    }

    // ---- transposed (bi < ct): col stats over this wave's 64 rows -> segment bi*2 + (w>>1) ----
    if (bi != ct) {
        #pragma unroll
        for (int fn = 0; fn < 4; ++fn) {
            const int lc = wc + fn * 16 + cl;
            const int gj = colbase + lc;
            const int lj = labC[lc];
            float m = -3.4e38f;
            #pragma unroll
            for (int fm = 0; fm < 4; ++fm)
                #pragma unroll
                for (int reg = 0; reg < 4; ++reg)
                    m = fmaxf(m, acc[fm][fn][reg] * invT);
            m = fmaxf(m, __shfl_xor(m, 16));
            m = fmaxf(m, __shfl_xor(m, 32));
            float se = 0.f, ps = 0.f, cnt = 0.f;
            #pragma unroll
            for (int fm = 0; fm < 4; ++fm) {
                #pragma unroll
                for (int reg = 0; reg < 4; ++reg) {
                    float c = acc[fm][fn][reg] * invT;
                    const int lr = wr + fm * 16 + cg * 4 + reg;
                    se += __expf(c - m);            // bi<ct: never self
                    const bool pos = (labR[lr] == lj);
                    ps += pos ? c : 0.f;
                    cnt += pos ? 1.f : 0.f;
                }
            }
            se += __shfl_xor(se, 16); ps += __shfl_xor(ps, 16); cnt += __shfl_xor(cnt, 16);
            se += __shfl_xor(se, 32); ps += __shfl_xor(ps, 32); cnt += __shfl_xor(cnt, 32);
            if (cg == 0)
                partials[(size_t)(bi * 2 + (w >> 1)) * NROW + gj] =
                    make_float4(m, se, ps, cnt);
        }
    }
}

// ---------------- Kernel D: per-row combine ----------------
__global__ void k_combine(const float4* __restrict__ partials, const float4* __restrict__ memq,
                          float* __restrict__ vals) {
    const int r = blockIdx.x * blockDim.x + threadIdx.x;
    if (r >= NROW) return;
    float M = -3.4e38f;
    #pragma unroll 8
    for (int s = 0; s < NSEG; ++s) M = fmaxf(M, partials[(size_t)s * NROW + r].x);
    float S1 = 0.f, ps = 0.f, cnt = 0.f;
    #pragma unroll 8
    for (int s = 0; s < NSEG; ++s) {
        float4 p = partials[(size_t)s * NROW + r];
        S1 += p.y * __expf(p.x - M);
        ps += p.z;
        cnt += p.w;
    }
    float4 mq = memq[r];
    float L = logf(S1 + mq.x);
    vals[r] = (ps - cnt * (M + L) + mq.y - mq.z * L) / (cnt + mq.z);
}

// ---------------- Kernel E: final scalar ----------------
__global__ void k_finalize(const float* __restrict__ vals, float* __restrict__ out) {
    const int t = threadIdx.x;          // 256
    const int lane = t & 63, wid = t >> 6;
    float s = 0.f;
    for (int i = t; i < NROW; i += 256) s += vals[i];
    #pragma unroll
    for (int d = 1; d < 64; d <<= 1) s += __shfl_xor(s, d);
    __shared__ float red[4];
    if (lane == 0) red[wid] = s;
    __syncthreads();
    if (t == 0) out[0] = -(red[0] + red[1] + red[2] + red[3]) * (1.0f / (float)NROW);
}

extern "C" void kernel_launch(void* const* d_in, const int* in_sizes, int n_in,
                              void* d_out, int out_size, void* d_ws, size_t ws_size,
                              hipStream_t stream) {
    const float* q  = (const float*)d_in[0];
    const int* labels = (const int*)d_in[1];
    const float* ml = (const float*)d_in[2];
    const float* mt = (const float*)d_in[3];
    float* out = (float*)d_out;

    char* w = (char*)d_ws;
    u16* qn          = (u16*)w;                      //  8,388,608 B
    float4* partials = (float4*)(w + 8388608);       //  4,194,304 B (64 segs)
    float4* memq     = (float4*)(w + 12582912);      //     65,536 B
    float* vals      = (float*)(w + 12648448);       //     16,384 B

    k_norm_mem<<<NROW, 256, 0, stream>>>(q, ml, mt, qn, memq);
    k_gemm_sym<<<NTRI, 256, 0, stream>>>(qn, labels, partials);
    k_combine<<<NROW / 256, 256, 0, stream>>>(partials, memq, vals);
    k_finalize<<<1, 256, 0, stream>>>(vals, out);
}

// Round 8
// 108.212 us; speedup vs baseline: 1.5166x; 1.0388x over previous
//
#include <hip/hip_runtime.h>
#include <hip/hip_bf16.h>
#include <math.h>

typedef unsigned short u16;
typedef __bf16 bf16x8 __attribute__((ext_vector_type(8)));
typedef float f32x4 __attribute__((ext_vector_type(4)));
typedef unsigned short u16x4 __attribute__((ext_vector_type(4)));

#define NROW 4096
#define KDIM 1024
#define MDIM 8192
#define TILE 128
#define BK 64
#define NT   (NROW / TILE)            // 32 tiles per dim
#define NSEG (NT * 2)                 // 64 col-segments of 64 cols
#define NTRI (NT * (NT + 1) / 2)      // 528 upper-triangle tiles = 8 * 66

__device__ __forceinline__ u16 f2bf(float x) {
    unsigned int u = __float_as_uint(x);
    unsigned int r = (u + 0x7fffu + ((u >> 16) & 1u)) >> 16;
    return (u16)r;
}

__device__ __forceinline__ void gload16(const u16* g, u16* l) {
    __builtin_amdgcn_global_load_lds(
        (const __attribute__((address_space(1))) void*)g,
        (__attribute__((address_space(3))) void*)l,
        16, 0, 0);
}

// ---------------- Kernel A+B fused: normalize row r AND memstats row r ----------------
// qn[r,:] = bf16(q[r,:]/max(||q[r,:]||,eps));  memq[r] = {S2, dot, smt, 0}
// Stream runs at the device read cap (~2.9 TB/s logical) — verified invariant
// across reg-ILP(2/8-deep), LDS-dbuf, and nt-load variants (R1/R3/R4/R7).
__global__ void k_norm_mem(const float* __restrict__ q,
                           const float* __restrict__ ml, const float* __restrict__ mt,
                           u16* __restrict__ qn, float4* __restrict__ memq) {
    const int r = blockIdx.x;
    const int t = threadIdx.x;          // 256
    const int lane = t & 63, wid = t >> 6;

    // --- issue q load + square-sum ---
    const float4* qr = (const float4*)(q + (size_t)r * KDIM);
    float4 v = qr[t];
    float ss = v.x * v.x + v.y * v.y + v.z * v.z + v.w * v.w;

    // --- memstats streaming (the big read) ---
    const float4* pl = (const float4*)(ml + (size_t)r * MDIM);
    const float4* pt = (const float4*)(mt + (size_t)r * MDIM);
    float S2 = 0.f, dot = 0.f, smt = 0.f;
    #pragma unroll
    for (int it = 0; it < 2; ++it) {
        const int i0 = it * 1024 + t;
        float4 l0 = pl[i0], l1 = pl[i0 + 256], l2 = pl[i0 + 512], l3 = pl[i0 + 768];
        float4 t0 = pt[i0], t1 = pt[i0 + 256], t2 = pt[i0 + 512], t3 = pt[i0 + 768];
        S2 += __expf(l0.x) + __expf(l0.y) + __expf(l0.z) + __expf(l0.w);
        S2 += __expf(l1.x) + __expf(l1.y) + __expf(l1.z) + __expf(l1.w);
        S2 += __expf(l2.x) + __expf(l2.y) + __expf(l2.z) + __expf(l2.w);
        S2 += __expf(l3.x) + __expf(l3.y) + __expf(l3.z) + __expf(l3.w);
        dot += t0.x * l0.x + t0.y * l0.y + t0.z * l0.z + t0.w * l0.w;
        dot += t1.x * l1.x + t1.y * l1.y + t1.z * l1.z + t1.w * l1.w;
        dot += t2.x * l2.x + t2.y * l2.y + t2.z * l2.z + t2.w * l2.w;
        dot += t3.x * l3.x + t3.y * l3.y + t3.z * l3.z + t3.w * l3.w;
        smt += t0.x + t0.y + t0.z + t0.w + t1.x + t1.y + t1.z + t1.w;
        smt += t2.x + t2.y + t2.z + t2.w + t3.x + t3.y + t3.z + t3.w;
    }

    // --- finish normalize ---
    #pragma unroll
    for (int d = 1; d < 64; d <<= 1) ss += __shfl_xor(ss, d);
    __shared__ float redn[4];
    if (lane == 0) redn[wid] = ss;
    __syncthreads();
    float tot = redn[0] + redn[1] + redn[2] + redn[3];
    float inv = 1.0f / fmaxf(sqrtf(tot), 1e-8f);
    u16x4 o;
    o[0] = f2bf(v.x * inv); o[1] = f2bf(v.y * inv);
    o[2] = f2bf(v.z * inv); o[3] = f2bf(v.w * inv);
    *(u16x4*)(qn + (size_t)r * KDIM + t * 4) = o;

    // --- finish memstats ---
    #pragma unroll
    for (int d = 1; d < 64; d <<= 1) {
        S2  += __shfl_xor(S2, d);
        dot += __shfl_xor(dot, d);
        smt += __shfl_xor(smt, d);
    }
    __shared__ float red[4][3];
    if (lane == 0) { red[wid][0] = S2; red[wid][1] = dot; red[wid][2] = smt; }
    __syncthreads();
    if (t == 0)
        memq[r] = make_float4(red[0][0] + red[1][0] + red[2][0] + red[3][0],
                              red[0][1] + red[1][1] + red[2][1] + red[3][1],
                              red[0][2] + red[1][2] + red[2][2] + red[3][2], 0.f);
}

// ---------------- Kernel C: symmetric sims GEMM + fused segment stats ----------------
// XCD-banded enumeration: XCD x = bid&7 owns a contiguous 66-slot slice of a
// chunk-coherent enumeration so its qn working set ~fits the 4 MB per-XCD L2.
__global__ void k_gemm_sym(const u16* __restrict__ qn, const int* __restrict__ labels,
                           float4* __restrict__ partials) {
    __shared__ u16 ldsA[TILE * BK];
    __shared__ u16 ldsB[TILE * BK];
    __shared__ int labR[TILE], labC[TILE];

    const int bid = blockIdx.x;
    int e = (bid & 7) * 66 + (bid >> 3);   // enumeration index in [0,528)
    // chunk order (rb,cb): (0,0)(0,1)(1,1)(0,2)(1,2)(2,2)(0,3)(1,3)(2,3)(3,3)
    int rb, cb, base;
    if      (e < 36)  { rb = 0; cb = 0; base = 0;   }
    else if (e < 100) { rb = 0; cb = 1; base = 36;  }
    else if (e < 136) { rb = 1; cb = 1; base = 100; }
    else if (e < 200) { rb = 0; cb = 2; base = 136; }
    else if (e < 264) { rb = 1; cb = 2; base = 200; }
    else if (e < 300) { rb = 2; cb = 2; base = 264; }
    else if (e < 364) { rb = 0; cb = 3; base = 300; }
    else if (e < 428) { rb = 1; cb = 3; base = 364; }
    else if (e < 492) { rb = 2; cb = 3; base = 428; }
    else              { rb = 3; cb = 3; base = 492; }
    int k = e - base;
    int bi, ct;
    if (rb == cb) {                       // triangular 8x8 chunk, k in [0,36)
        int b2 = 0, kk = k;
        while (kk >= 8 - b2) { kk -= 8 - b2; ++b2; }
        bi = rb * 8 + b2; ct = cb * 8 + b2 + kk;
    } else {                              // full 8x8 chunk
        bi = rb * 8 + (k >> 3); ct = cb * 8 + (k & 7);
    }

    const int t = threadIdx.x;
    const int w = t >> 6, lane = t & 63;
    const int rowbase = bi * TILE, colbase = ct * TILE;

    if (t < 128) labR[t] = labels[rowbase + t];
    else labC[t - 128] = labels[colbase + (t - 128)];

    const int wr = (w >> 1) * 64, wc = (w & 1) * 64;
    const int cl = lane & 15, cg = lane >> 4;
    const int sr = lane >> 3, skb = lane & 7;

    f32x4 acc[4][4];
    #pragma unroll
    for (int i = 0; i < 4; ++i)
        #pragma unroll
        for (int j = 0; j < 4; ++j)
            acc[i][j] = {0.f, 0.f, 0.f, 0.f};

    for (int ks = 0; ks < KDIM / BK; ++ks) {
        const int k0 = ks * BK;
        #pragma unroll
        for (int it = 0; it < 4; ++it) {
            int c = w * 4 + it;
            int rw = c * 8 + sr;
            gload16(qn + (size_t)(rowbase + rw) * KDIM + k0 + skb * 8, ldsA + c * 512);
            gload16(qn + (size_t)(colbase + rw) * KDIM + k0 + skb * 8, ldsB + c * 512);
        }
        asm volatile("s_waitcnt vmcnt(0)" ::: "memory");
        __syncthreads();
        #pragma unroll
        for (int k2 = 0; k2 < 2; ++k2) {
            bf16x8 a[4], b[4];
            #pragma unroll
            for (int f = 0; f < 4; ++f) {
                a[f] = *(const bf16x8*)&ldsA[(wr + f * 16 + cl) * BK + k2 * 32 + cg * 8];
                b[f] = *(const bf16x8*)&ldsB[(wc + f * 16 + cl) * BK + k2 * 32 + cg * 8];
            }
            #pragma unroll
            for (int fm = 0; fm < 4; ++fm)
                #pragma unroll
                for (int fn = 0; fn < 4; ++fn)
                    acc[fm][fn] = __builtin_amdgcn_mfma_f32_16x16x32_bf16(
                        a[fm], b[fn], acc[fm][fn], 0, 0, 0);
        }
        __syncthreads();
    }

    const float invT = (float)(1.0 / 0.07);

    // ---- direct: row stats over this wave's 64 cols -> segment ct*2 + (w&1) ----
    // C-layout (m89): col = lane&15, row = (lane>>4)*4 + reg.
    #pragma unroll
    for (int fm = 0; fm < 4; ++fm) {
        #pragma unroll
        for (int reg = 0; reg < 4; ++reg) {
            const int lr = wr + fm * 16 + cg * 4 + reg;
            const int gi = rowbase + lr;
            const int li = labR[lr];
            float c0 = acc[fm][0][reg] * invT;
            float c1 = acc[fm][1][reg] * invT;
            float c2 = acc[fm][2][reg] * invT;
            float c3 = acc[fm][3][reg] * invT;
            float m = fmaxf(fmaxf(c0, c1), fmaxf(c2, c3));
            #pragma unroll
            for (int d = 1; d < 16; d <<= 1) m = fmaxf(m, __shfl_xor(m, d));
            float se = 0.f, ps = 0.f, cnt = 0.f;
            #pragma unroll
            for (int fn = 0; fn < 4; ++fn) {
                float c = (fn == 0) ? c0 : (fn == 1) ? c1 : (fn == 2) ? c2 : c3;
                const int lc = wc + fn * 16 + cl;
                const bool self = (colbase + lc == gi);
                se += self ? 0.f : __expf(c - m);
                const bool pos = (!self) && (labC[lc] == li);
                ps += pos ? c : 0.f;
                cnt += pos ? 1.f : 0.f;
            }
            #pragma unroll
            for (int d = 1; d < 16; d <<= 1) {
                se  += __shfl_xor(se, d);
                ps  += __shfl_xor(ps, d);
                cnt += __shfl_xor(cnt, d);
            }
            if (cl == 0)
                partials[(size_t)(ct * 2 + (w & 1)) * NROW + gi] =
                    make_float4(m, se, ps, cnt);
        }
    }

    // ---- transposed (bi < ct): col stats over this wave's 64 rows -> segment bi*2 + (w>>1) ----
    if (bi != ct) {
        #pragma unroll
        for (int fn = 0; fn < 4; ++fn) {
            const int lc = wc + fn * 16 + cl;
            const int gj = colbase + lc;
            const int lj = labC[lc];
            float m = -3.4e38f;
            #pragma unroll
            for (int fm = 0; fm < 4; ++fm)
                #pragma unroll
                for (int reg = 0; reg < 4; ++reg)
                    m = fmaxf(m, acc[fm][fn][reg] * invT);
            m = fmaxf(m, __shfl_xor(m, 16));
            m = fmaxf(m, __shfl_xor(m, 32));
            float se = 0.f, ps = 0.f, cnt = 0.f;
            #pragma unroll
            for (int fm = 0; fm < 4; ++fm) {
                #pragma unroll
                for (int reg = 0; reg < 4; ++reg) {
                    float c = acc[fm][fn][reg] * invT;
                    const int lr = wr + fm * 16 + cg * 4 + reg;
                    se += __expf(c - m);            // bi<ct: never self
                    const bool pos = (labR[lr] == lj);
                    ps += pos ? c : 0.f;
                    cnt += pos ? 1.f : 0.f;
                }
            }
            se += __shfl_xor(se, 16); ps += __shfl_xor(ps, 16); cnt += __shfl_xor(cnt, 16);
            se += __shfl_xor(se, 32); ps += __shfl_xor(ps, 32); cnt += __shfl_xor(cnt, 32);
            if (cg == 0)
                partials[(size_t)(bi * 2 + (w >> 1)) * NROW + gj] =
                    make_float4(m, se, ps, cnt);
        }
    }
}

// ---------------- Kernel D: per-row combine ----------------
__global__ void k_combine(const float4* __restrict__ partials, const float4* __restrict__ memq,
                          float* __restrict__ vals) {
    const int r = blockIdx.x * blockDim.x + threadIdx.x;
    if (r >= NROW) return;
    float M = -3.4e38f;
    #pragma unroll 8
    for (int s = 0; s < NSEG; ++s) M = fmaxf(M, partials[(size_t)s * NROW + r].x);
    float S1 = 0.f, ps = 0.f, cnt = 0.f;
    #pragma unroll 8
    for (int s = 0; s < NSEG; ++s) {
        float4 p = partials[(size_t)s * NROW + r];
        S1 += p.y * __expf(p.x - M);
        ps += p.z;
        cnt += p.w;
    }
    float4 mq = memq[r];
    float L = logf(S1 + mq.x);
    vals[r] = (ps - cnt * (M + L) + mq.y - mq.z * L) / (cnt + mq.z);
}

// ---------------- Kernel E: final scalar ----------------
__global__ void k_finalize(const float* __restrict__ vals, float* __restrict__ out) {
    const int t = threadIdx.x;          // 256
    const int lane = t & 63, wid = t >> 6;
    float s = 0.f;
    for (int i = t; i < NROW; i += 256) s += vals[i];
    #pragma unroll
    for (int d = 1; d < 64; d <<= 1) s += __shfl_xor(s, d);
    __shared__ float red[4];
    if (lane == 0) red[wid] = s;
    __syncthreads();
    if (t == 0) out[0] = -(red[0] + red[1] + red[2] + red[3]) * (1.0f / (float)NROW);
}

extern "C" void kernel_launch(void* const* d_in, const int* in_sizes, int n_in,
                              void* d_out, int out_size, void* d_ws, size_t ws_size,
                              hipStream_t stream) {
    const float* q  = (const float*)d_in[0];
    const int* labels = (const int*)d_in[1];
    const float* ml = (const float*)d_in[2];
    const float* mt = (const float*)d_in[3];
    float* out = (float*)d_out;

    char* w = (char*)d_ws;
    u16* qn          = (u16*)w;                      //  8,388,608 B
    float4* partials = (float4*)(w + 8388608);       //  4,194,304 B (64 segs)
    float4* memq     = (float4*)(w + 12582912);      //     65,536 B
    float* vals      = (float*)(w + 12648448);       //     16,384 B

    k_norm_mem<<<NROW, 256, 0, stream>>>(q, ml, mt, qn, memq);
    k_gemm_sym<<<NTRI, 256, 0, stream>>>(qn, labels, partials);
    k_combine<<<NROW / 256, 256, 0, stream>>>(partials, memq, vals);
    k_finalize<<<1, 256, 0, stream>>>(vals, out);
}